// Round 4
// baseline (1421.746 us; speedup 1.0000x reference)
//
#include <hip/hip_runtime.h>

// MPT attention w/ ALiBi: B=4 S=2048 D=2048 H=16 HD=128, fp32 in/out,
// bf16 MFMA pipeline.
//
// Pipeline:
//   1. transpose_cvt: Wqkv -> WqkvT bf16 [6144][2048], Wout -> WoutT bf16 [2048][2048]
//   2. cvt_bf16: x fp32 -> xb bf16 [8192][2048] (stored in d_out scratch)
//   3. gemm_qkv: qkv = xb @ Wqkv + b ; 128x256x32 tiles, global_load_lds staging.
//      Writes Q,K [B,H,S,HD], V^T [B,H,HD,S].
//   4. attn: flash attention, 512 thr / 8 waves, q-block 128. K/V staged via
//      global_load_lds into linear [128][128] LDS with T2 XOR-swizzle
//      (pre-swizzled global source + swizzled reads). P overlays sK, same swizzle.
//   5. gemm_out: out = O @ Wout + b_out; 128x128x32, global_load_lds staging
//
// ws layout (128 MiB): [0) WqkvT 24M ][24M) WoutT 8M ][32M) Q/O 32M ][64M) K 32M ][96M) V^T 32M ]

typedef unsigned short u16;
typedef unsigned int u32;
typedef u16  u16x8 __attribute__((ext_vector_type(8)));
typedef __bf16 bf16x8 __attribute__((ext_vector_type(8)));
typedef float f32x4 __attribute__((ext_vector_type(4)));

__device__ __forceinline__ u16 f2b(float f) {
  union { float f; unsigned u; } v; v.f = f;
  return (u16)((v.u + 0x7fffu + ((v.u >> 16) & 1u)) >> 16);  // RNE
}

// pack two fp32 -> two bf16 (RNE-ish) in one v_perm: [lo16=bf16(a) | hi16=bf16(b)]
__device__ __forceinline__ u32 pk2(float a, float b) {
  u32 ua = __float_as_uint(a) + 0x8000u;
  u32 ub = __float_as_uint(b) + 0x8000u;
  return __builtin_amdgcn_perm(ub, ua, 0x07060302u);
}

__device__ __forceinline__ f32x4 mfma16(bf16x8 a, bf16x8 b, f32x4 c) {
  return __builtin_amdgcn_mfma_f32_16x16x32_bf16(a, b, c, 0, 0, 0);
}
__device__ __forceinline__ bf16x8 ldb(const u16* p) { return *(const bf16x8*)p; }

// async global->LDS, 16B per lane. LDS dest is wave-uniform base + lane*16.
__device__ __forceinline__ void g2l16(const u16* g, u16* l) {
  __builtin_amdgcn_global_load_lds(
      (const __attribute__((address_space(1))) unsigned int*)g,
      (__attribute__((address_space(3))) unsigned int*)l, 16, 0, 0);
}

// ---------------------------------------------------------------- transpose+cvt
__global__ __launch_bounds__(256) void transpose_cvt(
    const float* __restrict__ src, u16* __restrict__ dst, int R, int C) {
  __shared__ float tile[32][33];
  const int c0 = blockIdx.x * 32, r0 = blockIdx.y * 32;
  const int tx = threadIdx.x & 31, ty = threadIdx.x >> 5;
  #pragma unroll
  for (int i = 0; i < 4; ++i)
    tile[ty + 8 * i][tx] = src[(size_t)(r0 + ty + 8 * i) * C + c0 + tx];
  __syncthreads();
  #pragma unroll
  for (int i = 0; i < 4; ++i)
    dst[(size_t)(c0 + ty + 8 * i) * R + r0 + tx] = f2b(tile[tx][ty + 8 * i]);
}

// ---------------------------------------------------------------- x fp32 -> bf16
__global__ __launch_bounds__(256) void cvt_bf16(
    const float* __restrict__ src, u16* __restrict__ dst) {
  const size_t i = ((size_t)blockIdx.x * 256 + threadIdx.x) * 8;
  f32x4 a = *(const f32x4*)(src + i);
  f32x4 b = *(const f32x4*)(src + i + 4);
  uint4 w;
  w.x = pk2(a[0], a[1]); w.y = pk2(a[2], a[3]);
  w.z = pk2(b[0], b[1]); w.w = pk2(b[2], b[3]);
  *(uint4*)(dst + i) = w;
}

// ---------------------------------------------------------------- GEMM1: QKV proj
// C[8192,6144] = xb @ Wqkv + b. 128x256x32 tiles, 4 waves (2m x 2n), 4x8 frags/wave.
// m97 structure: global_load_lds width=16, single LDS buffer, 2 barriers/K-step.
__global__ __launch_bounds__(256, 2) void gemm_qkv(
    const u16* __restrict__ xb, const u16* __restrict__ wT,
    const float* __restrict__ bias,
    u16* __restrict__ qbuf, u16* __restrict__ kbuf, u16* __restrict__ vbuf) {
  __shared__ u16 smem[128 * 136];   // loop: sA[128*32] + sB[256*32] = 24KB; epi: [128][136]
  u16* sA = smem;
  u16* sB = smem + 128 * 32;
  const int tid = threadIdx.x;
  const int lane = tid & 63, wv = tid >> 6;
  const int L = lane & 15, g = lane >> 4;
  const int wm = (wv >> 1) * 64, wn = (wv & 1) * 128;
  const int m0 = blockIdx.y * 128, n0 = blockIdx.x * 256;
  const int row = tid >> 1, sh = tid & 1;

  // staging geometry: each 1KB gload covers 16 rows x 32 cols bf16;
  // lane l -> row 16j + (l>>2), col (l&3)*8
  const int lr = lane >> 2, lc = (lane & 3) * 8;
  const u16* gA0 = xb + (size_t)(m0 + 32 * wv + lr) * 2048 + lc;
  const u16* gA1 = gA0 + (size_t)16 * 2048;
  const u16* gB0 = wT + (size_t)(n0 + 64 * wv + lr) * 2048 + lc;
  const u16* gB1 = gB0 + (size_t)16 * 2048;
  const u16* gB2 = gB0 + (size_t)32 * 2048;
  const u16* gB3 = gB0 + (size_t)48 * 2048;
  u16* lA0 = &sA[1024 * wv];
  u16* lA1 = &sA[1024 * wv + 512];
  u16* lB0 = &sB[2048 * wv];
  u16* lB1 = &sB[2048 * wv + 512];
  u16* lB2 = &sB[2048 * wv + 1024];
  u16* lB3 = &sB[2048 * wv + 1536];

  f32x4 acc[4][8] = {};

  for (int kt = 0; kt < 64; ++kt) {
    __syncthreads();  // prior compute's LDS reads complete
    g2l16(gA0, lA0); g2l16(gA1, lA1);
    g2l16(gB0, lB0); g2l16(gB1, lB1); g2l16(gB2, lB2); g2l16(gB3, lB3);
    gA0 += 32; gA1 += 32; gB0 += 32; gB1 += 32; gB2 += 32; gB3 += 32;
    __syncthreads();  // compiler drains vmcnt(0) -> LDS holds tile kt

    bf16x8 af[4], bfr[8];
    #pragma unroll
    for (int t = 0; t < 4; ++t) af[t] = ldb(&sA[(wm + 16 * t + L) * 32 + 8 * g]);
    #pragma unroll
    for (int t = 0; t < 8; ++t) bfr[t] = ldb(&sB[(wn + 16 * t + L) * 32 + 8 * g]);
    #pragma unroll
    for (int ti = 0; ti < 4; ++ti)
      #pragma unroll
      for (int tj = 0; tj < 8; ++tj)
        acc[ti][tj] = mfma16(af[ti], bfr[tj], acc[ti][tj]);
  }

  float bs[8];
  #pragma unroll
  for (int tj = 0; tj < 8; ++tj) bs[tj] = bias[n0 + wn + 16 * tj + L];

  const int bg = m0 >> 11, s0 = m0 & 2047;
  // two 128-col epilogue phases through [128][136] LDS
  #pragma unroll
  for (int p = 0; p < 2; ++p) {
    __syncthreads();
    if ((wv & 1) == p) {
      #pragma unroll
      for (int ti = 0; ti < 4; ++ti)
        #pragma unroll
        for (int tj = 0; tj < 8; ++tj)
          #pragma unroll
          for (int r = 0; r < 4; ++r)
            smem[(wm + 16 * ti + 4 * g + r) * 136 + 16 * tj + L] =
                f2b(acc[ti][tj][r] + bs[tj]);
    }
    __syncthreads();
    const int nb = n0 + p * 128;
    const int t3 = nb >> 11, hh = (nb & 2047) >> 7;
    if (t3 < 2) {
      u16* dst = (t3 == 0 ? qbuf : kbuf) + ((size_t)(bg * 16 + hh) * 2048 + s0) * 128;
      #pragma unroll
      for (int mm = 0; mm < 8; ++mm)
        *(u16x8*)&dst[row * 128 + sh * 64 + 8 * mm] =
            *(const u16x8*)&smem[row * 136 + sh * 64 + 8 * mm];
    } else {
      u16* dst = vbuf + (size_t)(bg * 16 + hh) * 128 * 2048 + s0;
      #pragma unroll
      for (int mm = 0; mm < 8; ++mm) {
        u16x8 v;
        #pragma unroll
        for (int jj = 0; jj < 8; ++jj) v[jj] = smem[(sh * 64 + 8 * mm + jj) * 136 + row];
        *(u16x8*)&dst[(size_t)row * 2048 + sh * 64 + 8 * mm] = v;
      }
    }
  }
}

// ---------------------------------------------------------------- flash attention
// 512 thr / 8 waves; block covers 128 q-rows (wave wv owns q0 = qt*128 + wv*16).
// K/V tiles [128][128] u16, LINEAR LDS, staged by global_load_lds with
// PRE-SWIZZLED global source: lane fetching LDS chunk c of row r reads global
// chunk c^(r&7). All LDS reads apply the same XOR -> bank-conflict-free.
// P (16x128 per wave) overlays sK with the same swizzle scheme.
extern __shared__ u16 dyn_smem[];
__global__ __launch_bounds__(512, 4) void attn(
    const u16* __restrict__ kbuf, const u16* __restrict__ vbuf,
    u16* __restrict__ qobuf) {
  u16* sK = dyn_smem;               // [128][128] (32 KB)
  u16* sV = dyn_smem + 128 * 128;   // [128][128] (32 KB)
  const int tid = threadIdx.x;
  const int lane = tid & 63, wv = tid >> 6;
  const int L = lane & 15, g = lane >> 4;
  const int qt = (int)gridDim.x - 1 - (int)blockIdx.x;  // heavy blocks first
  const int h = blockIdx.y, b = blockIdx.z;
  const int q0 = qt * 128 + wv * 16;
  const size_t bh = (size_t)(b * 16 + h);

  const u16* Qp = qobuf + (bh * 2048 + q0) * 128;
  bf16x8 qf[4];
  #pragma unroll
  for (int ks = 0; ks < 4; ++ks) qf[ks] = ldb(&Qp[L * 128 + ks * 32 + 8 * g]);

  // log2-domain softmax: fold log2(e) into scale and slope, use exp2f directly
  const float LOG2E = 1.4426950408889634f;
  const float slope2 = exp2f(-0.5f * (float)(h + 1)) * LOG2E;
  const float scale2 = 0.08838834764831845f * LOG2E;
  float m_[4] = {-1e30f, -1e30f, -1e30f, -1e30f};
  float l_[4] = {0.f, 0.f, 0.f, 0.f};
  f32x4 oa[8] = {};
  u16* sP = sK + wv * 16 * 128;  // wave-private 16x128 overlay inside sK

  // staging geometry: wave wv stages rows [wv*16, wv*16+16) of K and of V^T.
  // load i covers rows wv*16+4i .. +3; lane l -> row +(l>>4), chunk (l&15).
  const int lrow = lane >> 4, lchk = lane & 15;
  const u16* Kbase = kbuf + bh * 2048 * 128;
  const u16* Vbase = vbuf + bh * 128 * 2048;

  const int jmax = qt;
  for (int j = 0; j <= jmax; ++j) {
    __syncthreads();  // prior iter's sP/sV reads complete (sK/sV free)
    {
      const u16* Kj = Kbase + (size_t)j * (128 * 128);
      const u16* Vj = Vbase + j * 128;
      #pragma unroll
      for (int i = 0; i < 4; ++i) {
        const int r = wv * 16 + 4 * i + lrow;
        const int sw = (lchk ^ (r & 7)) * 8;  // pre-swizzled source chunk
        g2l16(Kj + (size_t)r * 128 + sw, sK + (wv * 16 + 4 * i) * 128);
        g2l16(Vj + (size_t)r * 2048 + sw, sV + (wv * 16 + 4 * i) * 128);
      }
    }
    __syncthreads();  // vmcnt(0) drain -> tiles j visible

    f32x4 sc[8] = {};
    __builtin_amdgcn_s_setprio(1);
    #pragma unroll
    for (int ks = 0; ks < 4; ++ks)
      #pragma unroll
      for (int tc = 0; tc < 8; ++tc) {
        bf16x8 kf = ldb(&sK[(16 * tc + L) * 128 + ((4 * ks + g) ^ (L & 7)) * 8]);
        sc[tc] = mfma16(qf[ks], kf, sc[tc]);
      }
    __builtin_amdgcn_s_setprio(0);

    float tmax[4] = {-1e30f, -1e30f, -1e30f, -1e30f};
    const int kbase = j * 128 + L;
    if (j == qt) {  // diagonal tile: causal mask (wave-uniform branch)
      #pragma unroll
      for (int tc = 0; tc < 8; ++tc) {
        const int kpos = kbase + 16 * tc;
        const float ab = slope2 * (float)(kpos - 2047);
        #pragma unroll
        for (int r = 0; r < 4; ++r) {
          float s = sc[tc][r] * scale2 + ab;
          if (kpos > q0 + 4 * g + r) s = -1e30f;
          sc[tc][r] = s;
          tmax[r] = fmaxf(tmax[r], s);
        }
      }
    } else {  // interior tile: no mask
      #pragma unroll
      for (int tc = 0; tc < 8; ++tc) {
        const float ab = slope2 * (float)(kbase + 16 * tc - 2047);
        #pragma unroll
        for (int r = 0; r < 4; ++r) {
          float s = sc[tc][r] * scale2 + ab;
          sc[tc][r] = s;
          tmax[r] = fmaxf(tmax[r], s);
        }
      }
    }
    #pragma unroll
    for (int r = 0; r < 4; ++r) {
      #pragma unroll
      for (int d = 1; d < 16; d <<= 1)
        tmax[r] = fmaxf(tmax[r], __shfl_xor(tmax[r], d, 64));
    }

    // defer-max: only rescale when some row grew by > 8 (log2 units); P <= 2^8
    const bool grow = (tmax[0] > m_[0] + 8.f) | (tmax[1] > m_[1] + 8.f) |
                      (tmax[2] > m_[2] + 8.f) | (tmax[3] > m_[3] + 8.f);
    if (__any(grow)) {
      #pragma unroll
      for (int r = 0; r < 4; ++r) {
        const float mn = fmaxf(m_[r], tmax[r]);
        const float al = exp2f(m_[r] - mn);
        m_[r] = mn;
        l_[r] *= al;
        #pragma unroll
        for (int tn = 0; tn < 8; ++tn) oa[tn][r] *= al;
      }
    }

    float ps[4] = {0.f, 0.f, 0.f, 0.f};
    #pragma unroll
    for (int tc = 0; tc < 8; ++tc)
      #pragma unroll
      for (int r = 0; r < 4; ++r) {
        float p = exp2f(sc[tc][r] - m_[r]);
        sc[tc][r] = p;
        ps[r] += p;
      }
    #pragma unroll
    for (int r = 0; r < 4; ++r) {
      #pragma unroll
      for (int d = 1; d < 16; d <<= 1) ps[r] += __shfl_xor(ps[r], d, 64);
      l_[r] += ps[r];
    }

    __syncthreads();  // all waves' QK^T sK reads done (sP overlays sK)

    // P write: row prow=4g+r, col 16tc+L -> chunk (2tc+(L>>3)) ^ (prow&7)
    #pragma unroll
    for (int tc = 0; tc < 8; ++tc)
      #pragma unroll
      for (int r = 0; r < 4; ++r) {
        const int prow = 4 * g + r;
        const int pchk = (2 * tc + (L >> 3)) ^ (prow & 7);
        sP[prow * 128 + pchk * 8 + (L & 7)] = f2b(sc[tc][r]);
      }

    __builtin_amdgcn_s_setprio(1);
    #pragma unroll
    for (int ks = 0; ks < 4; ++ks) {
      bf16x8 pf = ldb(&sP[L * 128 + ((4 * ks + g) ^ (L & 7)) * 8]);
      #pragma unroll
      for (int tn = 0; tn < 8; ++tn) {
        bf16x8 vf = ldb(&sV[(16 * tn + L) * 128 + ((4 * ks + g) ^ (L & 7)) * 8]);
        oa[tn] = mfma16(pf, vf, oa[tn]);
      }
    }
    __builtin_amdgcn_s_setprio(0);
  }

  u16* Op = qobuf + (bh * 2048 + q0) * 128;
  float inv[4];
  #pragma unroll
  for (int r = 0; r < 4; ++r) inv[r] = 1.0f / l_[r];
  #pragma unroll
  for (int tn = 0; tn < 8; ++tn)
    #pragma unroll
    for (int r = 0; r < 4; ++r)
      Op[(4 * g + r) * 128 + 16 * tn + L] = f2b(oa[tn][r] * inv[r]);
}

// ---------------------------------------------------------------- GEMM2: out proj
// out[8192,2048] = O @ Wout + b_out. 128x128x32 tiles, global_load_lds staging.
__global__ __launch_bounds__(256) void gemm_out(
    const u16* __restrict__ obuf, const u16* __restrict__ wT,
    const float* __restrict__ bias, float* __restrict__ out) {
  __shared__ u16 smem[128 * 64];  // sA[128*32] + sB[128*32]
  u16* sA = smem;
  u16* sB = smem + 128 * 32;
  const int tid = threadIdx.x;
  const int lane = tid & 63, wv = tid >> 6;
  const int L = lane & 15, g = lane >> 4;
  const int wm = (wv >> 1) * 64, wn = (wv & 1) * 64;
  const int m0 = blockIdx.y * 128, n0 = blockIdx.x * 128;
  const int bg = m0 >> 11, s0 = m0 & 2047;

  // staging: lane l -> row 16j + (l>>2), col (l&3)*8 ; j = 2*wv + {0,1}
  const int lr = lane >> 2, lc = (lane & 3) * 8;
  // A: O in [B,H,S,HD]; k = kt*32 + lc -> head kt>>2, within-head col (kt&3)*32 + lc
  const u16* aA0 = obuf + ((size_t)(bg * 16) * 2048 + s0 + 32 * wv + lr) * 128 + lc;
  const u16* aA1 = aA0 + (size_t)16 * 128;
  const u16* gB0 = wT + (size_t)(n0 + 32 * wv + lr) * 2048 + lc;
  const u16* gB1 = gB0 + (size_t)16 * 2048;
  u16* lA0 = &sA[1024 * wv];
  u16* lA1 = &sA[1024 * wv + 512];
  u16* lB0 = &sB[1024 * wv];
  u16* lB1 = &sB[1024 * wv + 512];

  f32x4 acc[4][4] = {};

  for (int kt = 0; kt < 64; ++kt) {
    __syncthreads();
    const size_t aoff = (size_t)(kt >> 2) * (2048 * 128) + (size_t)((kt & 3) * 32);
    g2l16(aA0 + aoff, lA0); g2l16(aA1 + aoff, lA1);
    g2l16(gB0, lB0); g2l16(gB1, lB1);
    gB0 += 32; gB1 += 32;
    __syncthreads();

    bf16x8 af[4], bfr[4];
    #pragma unroll
    for (int t = 0; t < 4; ++t) af[t] = ldb(&sA[(wm + 16 * t + L) * 32 + 8 * g]);
    #pragma unroll
    for (int t = 0; t < 4; ++t) bfr[t] = ldb(&sB[(wn + 16 * t + L) * 32 + 8 * g]);
    #pragma unroll
    for (int ti = 0; ti < 4; ++ti)
      #pragma unroll
      for (int tj = 0; tj < 4; ++tj)
        acc[ti][tj] = mfma16(af[ti], bfr[tj], acc[ti][tj]);
  }

  float bs[4];
  #pragma unroll
  for (int tj = 0; tj < 4; ++tj) bs[tj] = bias[n0 + wn + 16 * tj + L];
  #pragma unroll
  for (int ti = 0; ti < 4; ++ti)
    #pragma unroll
    for (int tj = 0; tj < 4; ++tj)
      #pragma unroll
      for (int r = 0; r < 4; ++r)
        out[(size_t)(m0 + wm + 16 * ti + 4 * g + r) * 2048 + n0 + wn + 16 * tj + L] =
            acc[ti][tj][r] + bs[tj];
}

// ---------------------------------------------------------------- launch
extern "C" void kernel_launch(void* const* d_in, const int* in_sizes, int n_in,
                              void* d_out, int out_size, void* d_ws, size_t ws_size,
                              hipStream_t stream) {
  const float* x    = (const float*)d_in[0];
  const float* Wqkv = (const float*)d_in[1];
  const float* bqkv = (const float*)d_in[2];
  const float* Wout = (const float*)d_in[3];
  const float* bout = (const float*)d_in[4];
  float* out = (float*)d_out;

  char* ws = (char*)d_ws;
  u16* wqkvT = (u16*)(ws + 0);           // 6144*2048*2  = 25165824
  u16* woutT = (u16*)(ws + 25165824);    // 2048*2048*2  =  8388608
  u16* qbuf  = (u16*)(ws + 33554432);    // 4*16*2048*128*2 = 33554432 (becomes O)
  u16* kbuf  = (u16*)(ws + 67108864);
  u16* vbuf  = (u16*)(ws + 100663296);   // transposed [B,H,HD,S]; total 128 MiB

  // x in bf16 lives in d_out (32 MiB of 64 MiB); gemm_out overwrites all of d_out later
  u16* xb = (u16*)d_out;

  transpose_cvt<<<dim3(192, 64), 256, 0, stream>>>(Wqkv, wqkvT, 2048, 6144);
  transpose_cvt<<<dim3(64, 64), 256, 0, stream>>>(Wout, woutT, 2048, 2048);
  cvt_bf16<<<8192, 256, 0, stream>>>(x, xb);
  gemm_qkv<<<dim3(24, 64), 256, 0, stream>>>(xb, wqkvT, bqkv, qbuf, kbuf, vbuf);
  attn<<<dim3(16, 16, 4), 512, 65536, stream>>>(kbuf, vbuf, qbuf);
  gemm_out<<<dim3(16, 64), 256, 0, stream>>>(qbuf, woutT, bout, out);
}

// Round 5
// 774.456 us; speedup vs baseline: 1.8358x; 1.8358x over previous
//
#include <hip/hip_runtime.h>

// MPT attention w/ ALiBi: B=4 S=2048 D=2048 H=16 HD=128, fp32 in/out,
// bf16 MFMA pipeline.
//
// Pipeline:
//   1. transpose_cvt: Wqkv -> WqkvT bf16 [6144][2048], Wout -> WoutT bf16 [2048][2048]
//   2. cvt_bf16: x fp32 -> xb bf16 [8192][2048] (stored in d_out scratch)
//   3. gemm_qkv: qkv = xb @ Wqkv + b ; 128x256x32 tiles, global_load_lds staging.
//      Writes Q,K [B,H,S,HD], V^T [B,H,HD,S].
//   4. attn: flash attention, 512 thr / 8 waves, q-block 128, branch-free inner
//      loop (r2-verified body), XCD-clustered grid: each XCD owns 8 (b,h) groups
//      so K/V j-step loads hit that XCD's L2.
//   5. gemm_out: out = O @ Wout + b_out; 128x128x32, global_load_lds staging
//
// ws layout (128 MiB): [0) WqkvT 24M ][24M) WoutT 8M ][32M) Q/O 32M ][64M) K 32M ][96M) V^T 32M ]

typedef unsigned short u16;
typedef unsigned int u32;
typedef u16  u16x8 __attribute__((ext_vector_type(8)));
typedef __bf16 bf16x8 __attribute__((ext_vector_type(8)));
typedef float f32x4 __attribute__((ext_vector_type(4)));

__device__ __forceinline__ u16 f2b(float f) {
  union { float f; unsigned u; } v; v.f = f;
  return (u16)((v.u + 0x7fffu + ((v.u >> 16) & 1u)) >> 16);  // RNE
}

// pack two fp32 -> two bf16 (RNE-ish) in one v_perm: [lo16=bf16(a) | hi16=bf16(b)]
__device__ __forceinline__ u32 pk2(float a, float b) {
  u32 ua = __float_as_uint(a) + 0x8000u;
  u32 ub = __float_as_uint(b) + 0x8000u;
  return __builtin_amdgcn_perm(ub, ua, 0x07060302u);
}

__device__ __forceinline__ f32x4 mfma16(bf16x8 a, bf16x8 b, f32x4 c) {
  return __builtin_amdgcn_mfma_f32_16x16x32_bf16(a, b, c, 0, 0, 0);
}
__device__ __forceinline__ bf16x8 ldb(const u16* p) { return *(const bf16x8*)p; }

// async global->LDS, 16B per lane. LDS dest is wave-uniform base + lane*16.
__device__ __forceinline__ void g2l16(const u16* g, u16* l) {
  __builtin_amdgcn_global_load_lds(
      (const __attribute__((address_space(1))) unsigned int*)g,
      (__attribute__((address_space(3))) unsigned int*)l, 16, 0, 0);
}

// ---------------------------------------------------------------- transpose+cvt
__global__ __launch_bounds__(256) void transpose_cvt(
    const float* __restrict__ src, u16* __restrict__ dst, int R, int C) {
  __shared__ float tile[32][33];
  const int c0 = blockIdx.x * 32, r0 = blockIdx.y * 32;
  const int tx = threadIdx.x & 31, ty = threadIdx.x >> 5;
  #pragma unroll
  for (int i = 0; i < 4; ++i)
    tile[ty + 8 * i][tx] = src[(size_t)(r0 + ty + 8 * i) * C + c0 + tx];
  __syncthreads();
  #pragma unroll
  for (int i = 0; i < 4; ++i)
    dst[(size_t)(c0 + ty + 8 * i) * R + r0 + tx] = f2b(tile[tx][ty + 8 * i]);
}

// ---------------------------------------------------------------- x fp32 -> bf16
__global__ __launch_bounds__(256) void cvt_bf16(
    const float* __restrict__ src, u16* __restrict__ dst) {
  const size_t i = ((size_t)blockIdx.x * 256 + threadIdx.x) * 8;
  f32x4 a = *(const f32x4*)(src + i);
  f32x4 b = *(const f32x4*)(src + i + 4);
  uint4 w;
  w.x = pk2(a[0], a[1]); w.y = pk2(a[2], a[3]);
  w.z = pk2(b[0], b[1]); w.w = pk2(b[2], b[3]);
  *(uint4*)(dst + i) = w;
}

// ---------------------------------------------------------------- GEMM1: QKV proj
// C[8192,6144] = xb @ Wqkv + b. 128x256x32 tiles, 4 waves (2m x 2n), 4x8 frags/wave.
// m97 structure: global_load_lds width=16, single LDS buffer, 2 barriers/K-step.
__global__ __launch_bounds__(256, 2) void gemm_qkv(
    const u16* __restrict__ xb, const u16* __restrict__ wT,
    const float* __restrict__ bias,
    u16* __restrict__ qbuf, u16* __restrict__ kbuf, u16* __restrict__ vbuf) {
  __shared__ u16 smem[128 * 136];   // loop: sA[128*32] + sB[256*32] = 24KB; epi: [128][136]
  u16* sA = smem;
  u16* sB = smem + 128 * 32;
  const int tid = threadIdx.x;
  const int lane = tid & 63, wv = tid >> 6;
  const int L = lane & 15, g = lane >> 4;
  const int wm = (wv >> 1) * 64, wn = (wv & 1) * 128;
  const int m0 = blockIdx.y * 128, n0 = blockIdx.x * 256;
  const int row = tid >> 1, sh = tid & 1;

  // staging geometry: each 1KB gload covers 16 rows x 32 cols bf16;
  // lane l -> row 16j + (l>>2), col (l&3)*8
  const int lr = lane >> 2, lc = (lane & 3) * 8;
  const u16* gA0 = xb + (size_t)(m0 + 32 * wv + lr) * 2048 + lc;
  const u16* gA1 = gA0 + (size_t)16 * 2048;
  const u16* gB0 = wT + (size_t)(n0 + 64 * wv + lr) * 2048 + lc;
  const u16* gB1 = gB0 + (size_t)16 * 2048;
  const u16* gB2 = gB0 + (size_t)32 * 2048;
  const u16* gB3 = gB0 + (size_t)48 * 2048;
  u16* lA0 = &sA[1024 * wv];
  u16* lA1 = &sA[1024 * wv + 512];
  u16* lB0 = &sB[2048 * wv];
  u16* lB1 = &sB[2048 * wv + 512];
  u16* lB2 = &sB[2048 * wv + 1024];
  u16* lB3 = &sB[2048 * wv + 1536];

  f32x4 acc[4][8] = {};

  for (int kt = 0; kt < 64; ++kt) {
    __syncthreads();  // prior compute's LDS reads complete
    g2l16(gA0, lA0); g2l16(gA1, lA1);
    g2l16(gB0, lB0); g2l16(gB1, lB1); g2l16(gB2, lB2); g2l16(gB3, lB3);
    gA0 += 32; gA1 += 32; gB0 += 32; gB1 += 32; gB2 += 32; gB3 += 32;
    __syncthreads();  // compiler drains vmcnt(0) -> LDS holds tile kt

    bf16x8 af[4], bfr[8];
    #pragma unroll
    for (int t = 0; t < 4; ++t) af[t] = ldb(&sA[(wm + 16 * t + L) * 32 + 8 * g]);
    #pragma unroll
    for (int t = 0; t < 8; ++t) bfr[t] = ldb(&sB[(wn + 16 * t + L) * 32 + 8 * g]);
    #pragma unroll
    for (int ti = 0; ti < 4; ++ti)
      #pragma unroll
      for (int tj = 0; tj < 8; ++tj)
        acc[ti][tj] = mfma16(af[ti], bfr[tj], acc[ti][tj]);
  }

  float bs[8];
  #pragma unroll
  for (int tj = 0; tj < 8; ++tj) bs[tj] = bias[n0 + wn + 16 * tj + L];

  const int bg = m0 >> 11, s0 = m0 & 2047;
  // two 128-col epilogue phases through [128][136] LDS
  #pragma unroll
  for (int p = 0; p < 2; ++p) {
    __syncthreads();
    if ((wv & 1) == p) {
      #pragma unroll
      for (int ti = 0; ti < 4; ++ti)
        #pragma unroll
        for (int tj = 0; tj < 8; ++tj)
          #pragma unroll
          for (int r = 0; r < 4; ++r)
            smem[(wm + 16 * ti + 4 * g + r) * 136 + 16 * tj + L] =
                f2b(acc[ti][tj][r] + bs[tj]);
    }
    __syncthreads();
    const int nb = n0 + p * 128;
    const int t3 = nb >> 11, hh = (nb & 2047) >> 7;
    if (t3 < 2) {
      u16* dst = (t3 == 0 ? qbuf : kbuf) + ((size_t)(bg * 16 + hh) * 2048 + s0) * 128;
      #pragma unroll
      for (int mm = 0; mm < 8; ++mm)
        *(u16x8*)&dst[row * 128 + sh * 64 + 8 * mm] =
            *(const u16x8*)&smem[row * 136 + sh * 64 + 8 * mm];
    } else {
      u16* dst = vbuf + (size_t)(bg * 16 + hh) * 128 * 2048 + s0;
      #pragma unroll
      for (int mm = 0; mm < 8; ++mm) {
        u16x8 v;
        #pragma unroll
        for (int jj = 0; jj < 8; ++jj) v[jj] = smem[(sh * 64 + 8 * mm + jj) * 136 + row];
        *(u16x8*)&dst[(size_t)row * 2048 + sh * 64 + 8 * mm] = v;
      }
    }
  }
}

// ---------------------------------------------------------------- flash attention
// 512 thr / 8 waves; block covers 128 q-rows (wave wv owns q0 = qt*128 + wv*16).
// Branch-free inner loop (predicated mask, unconditional rescale) — verified r2 body.
// Grid: 1D 1024 blocks, XCD-clustered decode: logical = (bid&7)*128 + (bid>>3),
// so XCD k owns logicals [128k,128k+128) = 8 whole (b,h) groups -> K/V stay in
// that XCD's L2 (1 MB per (b,h) vs 4 MiB L2). Heavy q-tiles first within each XCD.
extern __shared__ u16 dyn_smem[];
__global__ __launch_bounds__(512, 4) void attn(
    const u16* __restrict__ kbuf, const u16* __restrict__ vbuf,
    u16* __restrict__ qobuf) {
  u16* sK = dyn_smem;              // [128][136]
  u16* sV = dyn_smem + 128 * 136;  // [128][136]
  const int tid = threadIdx.x;
  const int lane = tid & 63, wv = tid >> 6;
  const int L = lane & 15, g = lane >> 4;
  const int bid = (int)blockIdx.x;
  const int logical = (bid & 7) * 128 + (bid >> 3);  // XCD-contiguous (1024 = 8*128)
  const int qt = 15 - (logical & 15);                // heavy blocks first
  const int bh_i = logical >> 4;                     // 0..63
  const int h = bh_i & 15, b = bh_i >> 4;
  const int q0 = qt * 128 + wv * 16;
  const size_t bh = (size_t)(b * 16 + h);
  const int row = tid >> 2, q4 = tid & 3;  // staging: 128 rows x 4 col-quarters

  const u16* Qp = qobuf + (bh * 2048 + q0) * 128;
  bf16x8 qf[4];
  #pragma unroll
  for (int ks = 0; ks < 4; ++ks) qf[ks] = ldb(&Qp[L * 128 + ks * 32 + 8 * g]);

  // log2-domain softmax: fold log2(e) into scale and slope, use exp2f directly
  const float LOG2E = 1.4426950408889634f;
  const float slope2 = exp2f(-0.5f * (float)(h + 1)) * LOG2E;
  const float scale2 = 0.08838834764831845f * LOG2E;
  float m_[4] = {-1e30f, -1e30f, -1e30f, -1e30f};
  float l_[4] = {0.f, 0.f, 0.f, 0.f};
  f32x4 oa[8] = {};
  u16* sP = sK + wv * 16 * 132;  // wave-private 16x132 region inside sK (8*2112 <= 17408)

  const int jmax = qt;  // keys needed up to qt*128+127
  for (int j = 0; j <= jmax; ++j) {
    __syncthreads();
    const u16* Kp = kbuf + (bh * 2048 + (size_t)j * 128) * 128;
    const u16* Vp = vbuf + bh * 128 * 2048 + j * 128;
    #pragma unroll
    for (int mm = 0; mm < 4; ++mm)
      *(u16x8*)&sK[row * 136 + q4 * 32 + 8 * mm] =
          *(const u16x8*)&Kp[row * 128 + q4 * 32 + 8 * mm];
    #pragma unroll
    for (int mm = 0; mm < 4; ++mm)
      *(u16x8*)&sV[row * 136 + q4 * 32 + 8 * mm] =
          *(const u16x8*)&Vp[(size_t)row * 2048 + q4 * 32 + 8 * mm];
    __syncthreads();

    f32x4 sc[8] = {};
    #pragma unroll
    for (int ks = 0; ks < 4; ++ks)
      #pragma unroll
      for (int tc = 0; tc < 8; ++tc) {
        bf16x8 kf = ldb(&sK[(16 * tc + L) * 136 + ks * 32 + 8 * g]);
        sc[tc] = mfma16(qf[ks], kf, sc[tc]);
      }

    float tmax[4] = {-1e30f, -1e30f, -1e30f, -1e30f};
    const int kbase = j * 128 + L;
    const bool need_mask = (j * 128 + 127) > q0;
    #pragma unroll
    for (int tc = 0; tc < 8; ++tc) {
      const int kpos = kbase + 16 * tc;
      const float ab = slope2 * (float)(kpos - 2047);
      #pragma unroll
      for (int r = 0; r < 4; ++r) {
        float s = sc[tc][r] * scale2 + ab;
        if (need_mask && kpos > q0 + 4 * g + r) s = -1e30f;
        sc[tc][r] = s;
        tmax[r] = fmaxf(tmax[r], s);
      }
    }
    #pragma unroll
    for (int r = 0; r < 4; ++r) {
      #pragma unroll
      for (int d = 1; d < 16; d <<= 1)
        tmax[r] = fmaxf(tmax[r], __shfl_xor(tmax[r], d, 64));
    }
    float al[4], ps[4];
    #pragma unroll
    for (int r = 0; r < 4; ++r) {
      float mn = fmaxf(m_[r], tmax[r]);
      al[r] = exp2f(m_[r] - mn);
      m_[r] = mn;
      ps[r] = 0.f;
    }
    #pragma unroll
    for (int tc = 0; tc < 8; ++tc)
      #pragma unroll
      for (int r = 0; r < 4; ++r) {
        float p = exp2f(sc[tc][r] - m_[r]);
        sc[tc][r] = p;
        ps[r] += p;
      }
    #pragma unroll
    for (int r = 0; r < 4; ++r) {
      #pragma unroll
      for (int d = 1; d < 16; d <<= 1) ps[r] += __shfl_xor(ps[r], d, 64);
      l_[r] = l_[r] * al[r] + ps[r];
    }
    #pragma unroll
    for (int tn = 0; tn < 8; ++tn)
      #pragma unroll
      for (int r = 0; r < 4; ++r) oa[tn][r] *= al[r];

    __syncthreads();
    #pragma unroll
    for (int tc = 0; tc < 8; ++tc)
      #pragma unroll
      for (int r = 0; r < 4; ++r)
        sP[(4 * g + r) * 132 + 16 * tc + L] = f2b(sc[tc][r]);

    #pragma unroll
    for (int ks = 0; ks < 4; ++ks) {
      bf16x8 pf = ldb(&sP[L * 132 + ks * 32 + 8 * g]);
      #pragma unroll
      for (int tn = 0; tn < 8; ++tn) {
        bf16x8 vf = ldb(&sV[(16 * tn + L) * 136 + ks * 32 + 8 * g]);
        oa[tn] = mfma16(pf, vf, oa[tn]);
      }
    }
  }

  u16* Op = qobuf + (bh * 2048 + q0) * 128;
  float inv[4];
  #pragma unroll
  for (int r = 0; r < 4; ++r) inv[r] = 1.0f / l_[r];
  #pragma unroll
  for (int tn = 0; tn < 8; ++tn)
    #pragma unroll
    for (int r = 0; r < 4; ++r)
      Op[(4 * g + r) * 128 + 16 * tn + L] = f2b(oa[tn][r] * inv[r]);
}

// ---------------------------------------------------------------- GEMM2: out proj
// out[8192,2048] = O @ Wout + b_out. 128x128x32 tiles, global_load_lds staging.
__global__ __launch_bounds__(256) void gemm_out(
    const u16* __restrict__ obuf, const u16* __restrict__ wT,
    const float* __restrict__ bias, float* __restrict__ out) {
  __shared__ u16 smem[128 * 64];  // sA[128*32] + sB[128*32]
  u16* sA = smem;
  u16* sB = smem + 128 * 32;
  const int tid = threadIdx.x;
  const int lane = tid & 63, wv = tid >> 6;
  const int L = lane & 15, g = lane >> 4;
  const int wm = (wv >> 1) * 64, wn = (wv & 1) * 64;
  const int m0 = blockIdx.y * 128, n0 = blockIdx.x * 128;
  const int bg = m0 >> 11, s0 = m0 & 2047;

  // staging: lane l -> row 16j + (l>>2), col (l&3)*8 ; j = 2*wv + {0,1}
  const int lr = lane >> 2, lc = (lane & 3) * 8;
  // A: O in [B,H,S,HD]; k = kt*32 + lc -> head kt>>2, within-head col (kt&3)*32 + lc
  const u16* aA0 = obuf + ((size_t)(bg * 16) * 2048 + s0 + 32 * wv + lr) * 128 + lc;
  const u16* aA1 = aA0 + (size_t)16 * 128;
  const u16* gB0 = wT + (size_t)(n0 + 32 * wv + lr) * 2048 + lc;
  const u16* gB1 = gB0 + (size_t)16 * 2048;
  u16* lA0 = &sA[1024 * wv];
  u16* lA1 = &sA[1024 * wv + 512];
  u16* lB0 = &sB[1024 * wv];
  u16* lB1 = &sB[1024 * wv + 512];

  f32x4 acc[4][4] = {};

  for (int kt = 0; kt < 64; ++kt) {
    __syncthreads();
    const size_t aoff = (size_t)(kt >> 2) * (2048 * 128) + (size_t)((kt & 3) * 32);
    g2l16(aA0 + aoff, lA0); g2l16(aA1 + aoff, lA1);
    g2l16(gB0, lB0); g2l16(gB1, lB1);
    gB0 += 32; gB1 += 32;
    __syncthreads();

    bf16x8 af[4], bfr[4];
    #pragma unroll
    for (int t = 0; t < 4; ++t) af[t] = ldb(&sA[(wm + 16 * t + L) * 32 + 8 * g]);
    #pragma unroll
    for (int t = 0; t < 4; ++t) bfr[t] = ldb(&sB[(wn + 16 * t + L) * 32 + 8 * g]);
    #pragma unroll
    for (int ti = 0; ti < 4; ++ti)
      #pragma unroll
      for (int tj = 0; tj < 4; ++tj)
        acc[ti][tj] = mfma16(af[ti], bfr[tj], acc[ti][tj]);
  }

  float bs[4];
  #pragma unroll
  for (int tj = 0; tj < 4; ++tj) bs[tj] = bias[n0 + wn + 16 * tj + L];
  #pragma unroll
  for (int ti = 0; ti < 4; ++ti)
    #pragma unroll
    for (int tj = 0; tj < 4; ++tj)
      #pragma unroll
      for (int r = 0; r < 4; ++r)
        out[(size_t)(m0 + wm + 16 * ti + 4 * g + r) * 2048 + n0 + wn + 16 * tj + L] =
            acc[ti][tj][r] + bs[tj];
}

// ---------------------------------------------------------------- launch
extern "C" void kernel_launch(void* const* d_in, const int* in_sizes, int n_in,
                              void* d_out, int out_size, void* d_ws, size_t ws_size,
                              hipStream_t stream) {
  const float* x    = (const float*)d_in[0];
  const float* Wqkv = (const float*)d_in[1];
  const float* bqkv = (const float*)d_in[2];
  const float* Wout = (const float*)d_in[3];
  const float* bout = (const float*)d_in[4];
  float* out = (float*)d_out;

  char* ws = (char*)d_ws;
  u16* wqkvT = (u16*)(ws + 0);           // 6144*2048*2  = 25165824
  u16* woutT = (u16*)(ws + 25165824);    // 2048*2048*2  =  8388608
  u16* qbuf  = (u16*)(ws + 33554432);    // 4*16*2048*128*2 = 33554432 (becomes O)
  u16* kbuf  = (u16*)(ws + 67108864);
  u16* vbuf  = (u16*)(ws + 100663296);   // transposed [B,H,HD,S]; total 128 MiB

  // x in bf16 lives in d_out (32 MiB of 64 MiB); gemm_out overwrites all of d_out later
  u16* xb = (u16*)d_out;

  transpose_cvt<<<dim3(192, 64), 256, 0, stream>>>(Wqkv, wqkvT, 2048, 6144);
  transpose_cvt<<<dim3(64, 64), 256, 0, stream>>>(Wout, woutT, 2048, 2048);
  cvt_bf16<<<8192, 256, 0, stream>>>(x, xb);
  gemm_qkv<<<dim3(24, 64), 256, 0, stream>>>(xb, wqkvT, bqkv, qbuf, kbuf, vbuf);
  attn<<<dim3(1024), 512, 69632, stream>>>(kbuf, vbuf, qbuf);
  gemm_out<<<dim3(16, 64), 256, 0, stream>>>(qbuf, woutT, bout, out);
}

// Round 6
// 747.652 us; speedup vs baseline: 1.9016x; 1.0359x over previous
//
#include <hip/hip_runtime.h>

// MPT attention w/ ALiBi: B=4 S=2048 D=2048 H=16 HD=128, fp32 in/out,
// bf16 MFMA pipeline.
//
// Pipeline:
//   1. transpose_cvt: Wqkv -> WqkvT bf16 [6144][2048], Wout -> WoutT bf16 [2048][2048]
//   2. cvt_bf16: x fp32 -> xb bf16 [8192][2048] (stored in d_out scratch)
//   3. gemm_qkv: qkv = xb @ Wqkv + b ; 128x256x32 tiles, global_load_lds staging.
//      Writes Q,K [B,H,S,HD], V^T [B,H,HD,S].
//   4. attn: flash attention, 512 thr / 8 waves, q-block 128, branch-free inner
//      loop, XCD-clustered grid, setprio around MFMA clusters.
//   5. gemm_out: out = O @ Wout + b_out; 128x256x32 tiles (same structure as
//      gemm_qkv), flat XCD-clustered 512-block grid, direct fp32 epilogue.
//
// ws layout (128 MiB): [0) WqkvT 24M ][24M) WoutT 8M ][32M) Q/O 32M ][64M) K 32M ][96M) V^T 32M ]

typedef unsigned short u16;
typedef unsigned int u32;
typedef u16  u16x8 __attribute__((ext_vector_type(8)));
typedef __bf16 bf16x8 __attribute__((ext_vector_type(8)));
typedef float f32x4 __attribute__((ext_vector_type(4)));

__device__ __forceinline__ u16 f2b(float f) {
  union { float f; unsigned u; } v; v.f = f;
  return (u16)((v.u + 0x7fffu + ((v.u >> 16) & 1u)) >> 16);  // RNE
}

// pack two fp32 -> two bf16 (RNE-ish) in one v_perm: [lo16=bf16(a) | hi16=bf16(b)]
__device__ __forceinline__ u32 pk2(float a, float b) {
  u32 ua = __float_as_uint(a) + 0x8000u;
  u32 ub = __float_as_uint(b) + 0x8000u;
  return __builtin_amdgcn_perm(ub, ua, 0x07060302u);
}

__device__ __forceinline__ f32x4 mfma16(bf16x8 a, bf16x8 b, f32x4 c) {
  return __builtin_amdgcn_mfma_f32_16x16x32_bf16(a, b, c, 0, 0, 0);
}
__device__ __forceinline__ bf16x8 ldb(const u16* p) { return *(const bf16x8*)p; }

// async global->LDS, 16B per lane. LDS dest is wave-uniform base + lane*16.
__device__ __forceinline__ void g2l16(const u16* g, u16* l) {
  __builtin_amdgcn_global_load_lds(
      (const __attribute__((address_space(1))) unsigned int*)g,
      (__attribute__((address_space(3))) unsigned int*)l, 16, 0, 0);
}

// ---------------------------------------------------------------- transpose+cvt
__global__ __launch_bounds__(256) void transpose_cvt(
    const float* __restrict__ src, u16* __restrict__ dst, int R, int C) {
  __shared__ float tile[32][33];
  const int c0 = blockIdx.x * 32, r0 = blockIdx.y * 32;
  const int tx = threadIdx.x & 31, ty = threadIdx.x >> 5;
  #pragma unroll
  for (int i = 0; i < 4; ++i)
    tile[ty + 8 * i][tx] = src[(size_t)(r0 + ty + 8 * i) * C + c0 + tx];
  __syncthreads();
  #pragma unroll
  for (int i = 0; i < 4; ++i)
    dst[(size_t)(c0 + ty + 8 * i) * R + r0 + tx] = f2b(tile[tx][ty + 8 * i]);
}

// ---------------------------------------------------------------- x fp32 -> bf16
__global__ __launch_bounds__(256) void cvt_bf16(
    const float* __restrict__ src, u16* __restrict__ dst) {
  const size_t i = ((size_t)blockIdx.x * 256 + threadIdx.x) * 8;
  f32x4 a = *(const f32x4*)(src + i);
  f32x4 b = *(const f32x4*)(src + i + 4);
  uint4 w;
  w.x = pk2(a[0], a[1]); w.y = pk2(a[2], a[3]);
  w.z = pk2(b[0], b[1]); w.w = pk2(b[2], b[3]);
  *(uint4*)(dst + i) = w;
}

// ---------------------------------------------------------------- GEMM1: QKV proj
// C[8192,6144] = xb @ Wqkv + b. 128x256x32 tiles, 4 waves (2m x 2n), 4x8 frags/wave.
// m97 structure: global_load_lds width=16, single LDS buffer, 2 barriers/K-step.
__global__ __launch_bounds__(256, 2) void gemm_qkv(
    const u16* __restrict__ xb, const u16* __restrict__ wT,
    const float* __restrict__ bias,
    u16* __restrict__ qbuf, u16* __restrict__ kbuf, u16* __restrict__ vbuf) {
  __shared__ u16 smem[128 * 136];   // loop: sA[128*32] + sB[256*32] = 24KB; epi: [128][136]
  u16* sA = smem;
  u16* sB = smem + 128 * 32;
  const int tid = threadIdx.x;
  const int lane = tid & 63, wv = tid >> 6;
  const int L = lane & 15, g = lane >> 4;
  const int wm = (wv >> 1) * 64, wn = (wv & 1) * 128;
  const int m0 = blockIdx.y * 128, n0 = blockIdx.x * 256;
  const int row = tid >> 1, sh = tid & 1;

  // staging geometry: each 1KB gload covers 16 rows x 32 cols bf16;
  // lane l -> row 16j + (l>>2), col (l&3)*8
  const int lr = lane >> 2, lc = (lane & 3) * 8;
  const u16* gA0 = xb + (size_t)(m0 + 32 * wv + lr) * 2048 + lc;
  const u16* gA1 = gA0 + (size_t)16 * 2048;
  const u16* gB0 = wT + (size_t)(n0 + 64 * wv + lr) * 2048 + lc;
  const u16* gB1 = gB0 + (size_t)16 * 2048;
  const u16* gB2 = gB0 + (size_t)32 * 2048;
  const u16* gB3 = gB0 + (size_t)48 * 2048;
  u16* lA0 = &sA[1024 * wv];
  u16* lA1 = &sA[1024 * wv + 512];
  u16* lB0 = &sB[2048 * wv];
  u16* lB1 = &sB[2048 * wv + 512];
  u16* lB2 = &sB[2048 * wv + 1024];
  u16* lB3 = &sB[2048 * wv + 1536];

  f32x4 acc[4][8] = {};

  for (int kt = 0; kt < 64; ++kt) {
    __syncthreads();  // prior compute's LDS reads complete
    g2l16(gA0, lA0); g2l16(gA1, lA1);
    g2l16(gB0, lB0); g2l16(gB1, lB1); g2l16(gB2, lB2); g2l16(gB3, lB3);
    gA0 += 32; gA1 += 32; gB0 += 32; gB1 += 32; gB2 += 32; gB3 += 32;
    __syncthreads();  // compiler drains vmcnt(0) -> LDS holds tile kt

    bf16x8 af[4], bfr[8];
    #pragma unroll
    for (int t = 0; t < 4; ++t) af[t] = ldb(&sA[(wm + 16 * t + L) * 32 + 8 * g]);
    #pragma unroll
    for (int t = 0; t < 8; ++t) bfr[t] = ldb(&sB[(wn + 16 * t + L) * 32 + 8 * g]);
    #pragma unroll
    for (int ti = 0; ti < 4; ++ti)
      #pragma unroll
      for (int tj = 0; tj < 8; ++tj)
        acc[ti][tj] = mfma16(af[ti], bfr[tj], acc[ti][tj]);
  }

  float bs[8];
  #pragma unroll
  for (int tj = 0; tj < 8; ++tj) bs[tj] = bias[n0 + wn + 16 * tj + L];

  const int bg = m0 >> 11, s0 = m0 & 2047;
  // two 128-col epilogue phases through [128][136] LDS
  #pragma unroll
  for (int p = 0; p < 2; ++p) {
    __syncthreads();
    if ((wv & 1) == p) {
      #pragma unroll
      for (int ti = 0; ti < 4; ++ti)
        #pragma unroll
        for (int tj = 0; tj < 8; ++tj)
          #pragma unroll
          for (int r = 0; r < 4; ++r)
            smem[(wm + 16 * ti + 4 * g + r) * 136 + 16 * tj + L] =
                f2b(acc[ti][tj][r] + bs[tj]);
    }
    __syncthreads();
    const int nb = n0 + p * 128;
    const int t3 = nb >> 11, hh = (nb & 2047) >> 7;
    if (t3 < 2) {
      u16* dst = (t3 == 0 ? qbuf : kbuf) + ((size_t)(bg * 16 + hh) * 2048 + s0) * 128;
      #pragma unroll
      for (int mm = 0; mm < 8; ++mm)
        *(u16x8*)&dst[row * 128 + sh * 64 + 8 * mm] =
            *(const u16x8*)&smem[row * 136 + sh * 64 + 8 * mm];
    } else {
      u16* dst = vbuf + (size_t)(bg * 16 + hh) * 128 * 2048 + s0;
      #pragma unroll
      for (int mm = 0; mm < 8; ++mm) {
        u16x8 v;
        #pragma unroll
        for (int jj = 0; jj < 8; ++jj) v[jj] = smem[(sh * 64 + 8 * mm + jj) * 136 + row];
        *(u16x8*)&dst[(size_t)row * 2048 + sh * 64 + 8 * mm] = v;
      }
    }
  }
}

// ---------------------------------------------------------------- flash attention
// 512 thr / 8 waves; block covers 128 q-rows (wave wv owns q0 = qt*128 + wv*16).
// Branch-free inner loop; XCD-clustered 1D grid; setprio around MFMA clusters.
extern __shared__ u16 dyn_smem[];
__global__ __launch_bounds__(512, 4) void attn(
    const u16* __restrict__ kbuf, const u16* __restrict__ vbuf,
    u16* __restrict__ qobuf) {
  u16* sK = dyn_smem;              // [128][136]
  u16* sV = dyn_smem + 128 * 136;  // [128][136]
  const int tid = threadIdx.x;
  const int lane = tid & 63, wv = tid >> 6;
  const int L = lane & 15, g = lane >> 4;
  const int bid = (int)blockIdx.x;
  const int logical = (bid & 7) * 128 + (bid >> 3);  // XCD-contiguous (1024 = 8*128)
  const int qt = 15 - (logical & 15);                // heavy blocks first
  const int bh_i = logical >> 4;                     // 0..63
  const int h = bh_i & 15, b = bh_i >> 4;
  const int q0 = qt * 128 + wv * 16;
  const size_t bh = (size_t)(b * 16 + h);
  const int row = tid >> 2, q4 = tid & 3;  // staging: 128 rows x 4 col-quarters

  const u16* Qp = qobuf + (bh * 2048 + q0) * 128;
  bf16x8 qf[4];
  #pragma unroll
  for (int ks = 0; ks < 4; ++ks) qf[ks] = ldb(&Qp[L * 128 + ks * 32 + 8 * g]);

  // log2-domain softmax: fold log2(e) into scale and slope, use exp2f directly
  const float LOG2E = 1.4426950408889634f;
  const float slope2 = exp2f(-0.5f * (float)(h + 1)) * LOG2E;
  const float scale2 = 0.08838834764831845f * LOG2E;
  float m_[4] = {-1e30f, -1e30f, -1e30f, -1e30f};
  float l_[4] = {0.f, 0.f, 0.f, 0.f};
  f32x4 oa[8] = {};
  u16* sP = sK + wv * 16 * 132;  // wave-private 16x132 region inside sK (8*2112 <= 17408)

  const int jmax = qt;  // keys needed up to qt*128+127
  for (int j = 0; j <= jmax; ++j) {
    __syncthreads();
    const u16* Kp = kbuf + (bh * 2048 + (size_t)j * 128) * 128;
    const u16* Vp = vbuf + bh * 128 * 2048 + j * 128;
    #pragma unroll
    for (int mm = 0; mm < 4; ++mm)
      *(u16x8*)&sK[row * 136 + q4 * 32 + 8 * mm] =
          *(const u16x8*)&Kp[row * 128 + q4 * 32 + 8 * mm];
    #pragma unroll
    for (int mm = 0; mm < 4; ++mm)
      *(u16x8*)&sV[row * 136 + q4 * 32 + 8 * mm] =
          *(const u16x8*)&Vp[(size_t)row * 2048 + q4 * 32 + 8 * mm];
    __syncthreads();

    f32x4 sc[8] = {};
    __builtin_amdgcn_s_setprio(1);
    #pragma unroll
    for (int ks = 0; ks < 4; ++ks)
      #pragma unroll
      for (int tc = 0; tc < 8; ++tc) {
        bf16x8 kf = ldb(&sK[(16 * tc + L) * 136 + ks * 32 + 8 * g]);
        sc[tc] = mfma16(qf[ks], kf, sc[tc]);
      }
    __builtin_amdgcn_s_setprio(0);

    float tmax[4] = {-1e30f, -1e30f, -1e30f, -1e30f};
    const int kbase = j * 128 + L;
    const bool need_mask = (j * 128 + 127) > q0;
    #pragma unroll
    for (int tc = 0; tc < 8; ++tc) {
      const int kpos = kbase + 16 * tc;
      const float ab = slope2 * (float)(kpos - 2047);
      #pragma unroll
      for (int r = 0; r < 4; ++r) {
        float s = sc[tc][r] * scale2 + ab;
        if (need_mask && kpos > q0 + 4 * g + r) s = -1e30f;
        sc[tc][r] = s;
        tmax[r] = fmaxf(tmax[r], s);
      }
    }
    #pragma unroll
    for (int r = 0; r < 4; ++r) {
      #pragma unroll
      for (int d = 1; d < 16; d <<= 1)
        tmax[r] = fmaxf(tmax[r], __shfl_xor(tmax[r], d, 64));
    }
    float al[4], ps[4];
    #pragma unroll
    for (int r = 0; r < 4; ++r) {
      float mn = fmaxf(m_[r], tmax[r]);
      al[r] = exp2f(m_[r] - mn);
      m_[r] = mn;
      ps[r] = 0.f;
    }
    #pragma unroll
    for (int tc = 0; tc < 8; ++tc)
      #pragma unroll
      for (int r = 0; r < 4; ++r) {
        float p = exp2f(sc[tc][r] - m_[r]);
        sc[tc][r] = p;
        ps[r] += p;
      }
    #pragma unroll
    for (int r = 0; r < 4; ++r) {
      #pragma unroll
      for (int d = 1; d < 16; d <<= 1) ps[r] += __shfl_xor(ps[r], d, 64);
      l_[r] = l_[r] * al[r] + ps[r];
    }
    #pragma unroll
    for (int tn = 0; tn < 8; ++tn)
      #pragma unroll
      for (int r = 0; r < 4; ++r) oa[tn][r] *= al[r];

    __syncthreads();
    #pragma unroll
    for (int tc = 0; tc < 8; ++tc)
      #pragma unroll
      for (int r = 0; r < 4; ++r)
        sP[(4 * g + r) * 132 + 16 * tc + L] = f2b(sc[tc][r]);

    __builtin_amdgcn_s_setprio(1);
    #pragma unroll
    for (int ks = 0; ks < 4; ++ks) {
      bf16x8 pf = ldb(&sP[L * 132 + ks * 32 + 8 * g]);
      #pragma unroll
      for (int tn = 0; tn < 8; ++tn) {
        bf16x8 vf = ldb(&sV[(16 * tn + L) * 136 + ks * 32 + 8 * g]);
        oa[tn] = mfma16(pf, vf, oa[tn]);
      }
    }
    __builtin_amdgcn_s_setprio(0);
  }

  u16* Op = qobuf + (bh * 2048 + q0) * 128;
  float inv[4];
  #pragma unroll
  for (int r = 0; r < 4; ++r) inv[r] = 1.0f / l_[r];
  #pragma unroll
  for (int tn = 0; tn < 8; ++tn)
    #pragma unroll
    for (int r = 0; r < 4; ++r)
      Op[(4 * g + r) * 128 + 16 * tn + L] = f2b(oa[tn][r] * inv[r]);
}

// ---------------------------------------------------------------- GEMM2: out proj
// out[8192,2048] = O @ Wout + b_out. 128x256x32 tiles (structural copy of gemm_qkv),
// 4 waves, 4x8 frags/wave, global_load_lds staging, direct fp32 epilogue.
// Flat 512-block grid, XCD-bijective: wg = (bid&7)*64 + bid>>3; mt = wg>>3, nt = wg&7.
__global__ __launch_bounds__(256, 2) void gemm_out(
    const u16* __restrict__ obuf, const u16* __restrict__ wT,
    const float* __restrict__ bias, float* __restrict__ out) {
  __shared__ u16 smem[128 * 32 + 256 * 32];  // sA[128x32] + sB[256x32] = 24KB
  u16* sA = smem;
  u16* sB = smem + 128 * 32;
  const int tid = threadIdx.x;
  const int lane = tid & 63, wv = tid >> 6;
  const int L = lane & 15, g = lane >> 4;
  const int wm = (wv >> 1) * 64, wn = (wv & 1) * 128;
  const int bid = (int)blockIdx.x;
  const int wg = (bid & 7) * 64 + (bid >> 3);       // bijective XCD cluster (512=8*64)
  const int m0 = (wg >> 3) * 128, n0 = (wg & 7) * 256;
  const int bg = m0 >> 11, s0 = m0 & 2047;

  // staging: lane l -> row +(l>>2), col (l&3)*8 within the 32-wide k-window
  const int lr = lane >> 2, lc = (lane & 3) * 8;
  // A: O in [B,H,S,HD]; k = kt*32 + lc -> head kt>>2, within-head col (kt&3)*32 + lc
  const u16* aA0 = obuf + ((size_t)(bg * 16) * 2048 + s0 + 32 * wv + lr) * 128 + lc;
  const u16* aA1 = aA0 + (size_t)16 * 128;
  const u16* gB0 = wT + (size_t)(n0 + 64 * wv + lr) * 2048 + lc;
  const u16* gB1 = gB0 + (size_t)16 * 2048;
  const u16* gB2 = gB0 + (size_t)32 * 2048;
  const u16* gB3 = gB0 + (size_t)48 * 2048;
  u16* lA0 = &sA[1024 * wv];
  u16* lA1 = &sA[1024 * wv + 512];
  u16* lB0 = &sB[2048 * wv];
  u16* lB1 = &sB[2048 * wv + 512];
  u16* lB2 = &sB[2048 * wv + 1024];
  u16* lB3 = &sB[2048 * wv + 1536];

  f32x4 acc[4][8] = {};

  for (int kt = 0; kt < 64; ++kt) {
    __syncthreads();
    const size_t aoff = (size_t)(kt >> 2) * (2048 * 128) + (size_t)((kt & 3) * 32);
    g2l16(aA0 + aoff, lA0); g2l16(aA1 + aoff, lA1);
    g2l16(gB0, lB0); g2l16(gB1, lB1); g2l16(gB2, lB2); g2l16(gB3, lB3);
    gB0 += 32; gB1 += 32; gB2 += 32; gB3 += 32;
    __syncthreads();

    bf16x8 af[4], bfr[8];
    #pragma unroll
    for (int t = 0; t < 4; ++t) af[t] = ldb(&sA[(wm + 16 * t + L) * 32 + 8 * g]);
    #pragma unroll
    for (int t = 0; t < 8; ++t) bfr[t] = ldb(&sB[(wn + 16 * t + L) * 32 + 8 * g]);
    #pragma unroll
    for (int ti = 0; ti < 4; ++ti)
      #pragma unroll
      for (int tj = 0; tj < 8; ++tj)
        acc[ti][tj] = mfma16(af[ti], bfr[tj], acc[ti][tj]);
  }

  float bs[8];
  #pragma unroll
  for (int tj = 0; tj < 8; ++tj) bs[tj] = bias[n0 + wn + 16 * tj + L];
  #pragma unroll
  for (int ti = 0; ti < 4; ++ti)
    #pragma unroll
    for (int tj = 0; tj < 8; ++tj)
      #pragma unroll
      for (int r = 0; r < 4; ++r)
        out[(size_t)(m0 + wm + 16 * ti + 4 * g + r) * 2048 + n0 + wn + 16 * tj + L] =
            acc[ti][tj][r] + bs[tj];
}

// ---------------------------------------------------------------- launch
extern "C" void kernel_launch(void* const* d_in, const int* in_sizes, int n_in,
                              void* d_out, int out_size, void* d_ws, size_t ws_size,
                              hipStream_t stream) {
  const float* x    = (const float*)d_in[0];
  const float* Wqkv = (const float*)d_in[1];
  const float* bqkv = (const float*)d_in[2];
  const float* Wout = (const float*)d_in[3];
  const float* bout = (const float*)d_in[4];
  float* out = (float*)d_out;

  char* ws = (char*)d_ws;
  u16* wqkvT = (u16*)(ws + 0);           // 6144*2048*2  = 25165824
  u16* woutT = (u16*)(ws + 25165824);    // 2048*2048*2  =  8388608
  u16* qbuf  = (u16*)(ws + 33554432);    // 4*16*2048*128*2 = 33554432 (becomes O)
  u16* kbuf  = (u16*)(ws + 67108864);
  u16* vbuf  = (u16*)(ws + 100663296);   // transposed [B,H,HD,S]; total 128 MiB

  // x in bf16 lives in d_out (32 MiB of 64 MiB); gemm_out overwrites all of d_out later
  u16* xb = (u16*)d_out;

  transpose_cvt<<<dim3(192, 64), 256, 0, stream>>>(Wqkv, wqkvT, 2048, 6144);
  transpose_cvt<<<dim3(64, 64), 256, 0, stream>>>(Wout, woutT, 2048, 2048);
  cvt_bf16<<<8192, 256, 0, stream>>>(x, xb);
  gemm_qkv<<<dim3(24, 64), 256, 0, stream>>>(xb, wqkvT, bqkv, qbuf, kbuf, vbuf);
  attn<<<dim3(1024), 512, 69632, stream>>>(kbuf, vbuf, qbuf);
  gemm_out<<<dim3(512), 256, 0, stream>>>(qbuf, woutT, bout, out);
}